// Round 2
// baseline (126.245 us; speedup 1.0000x reference)
//
#include <hip/hip_runtime.h>

typedef __attribute__((ext_vector_type(8))) short short8;
typedef __attribute__((ext_vector_type(16))) float f32x16;

#define B_    8
#define N_TOK 4096
#define C_    512
#define H_    16
#define K_TOK 1024
#define D_    64
#define BM    128
#define BK    64

// fp32 -> bf16, round-to-nearest-even (inputs are finite randn; NaN path not needed)
static __device__ inline ushort f2b(float f) {
  unsigned u = __builtin_bit_cast(unsigned, f);
  u += 0x7fff + ((u >> 16) & 1);
  return (ushort)(u >> 16);
}

// W fp32 [H][C][D] -> WT bf16 [H][D][C]  (1 MB workspace)
__global__ __launch_bounds__(256) void wt_convert(const float* __restrict__ W,
                                                  ushort* __restrict__ WT) {
  int t = blockIdx.x * 256 + threadIdx.x;   // 524288 total
  int h = t >> 15;          // / (D_*C_)
  int rem = t & 32767;
  int n = rem >> 9;         // / C_
  int k = rem & 511;
  WT[t] = f2b(W[((size_t)(h << 9) + k) * D_ + n]);
}

__global__ __launch_bounds__(256) void gather_gemm(
    const float* __restrict__ X, const int* __restrict__ ind,
    const ushort* __restrict__ WT, float* __restrict__ out) {
  __shared__ ushort Asu[BM * BK];   // 16 KB, row = 64 ushorts (128 B), XOR-swizzled 16B chunks
  __shared__ ushort Bsu[D_ * BK];   // 8 KB, same swizzle
  __shared__ int inds[BM];

  int bid = blockIdx.x;
  // XCD swizzle: 1024 blocks, 8 XCDs -> XCD x gets contiguous batch x's blocks
  int nb = (bid & 7) * 128 + (bid >> 3);
  int b  = nb >> 7;
  int h  = (nb >> 3) & 15;
  int mt = nb & 7;

  int tid = threadIdx.x;
  if (tid < BM) inds[tid] = ind[(size_t)(b * H_ + h) * K_TOK + mt * BM + tid];
  __syncthreads();

  int lane = tid & 63;
  int wave = tid >> 6;
  int r16  = tid >> 4;   // 0..15  (staging row group)
  int c4   = tid & 15;   // 0..15  (staging col group, 4 floats each)

  f32x16 acc0 = {};
  f32x16 acc1 = {};

  const float*  Xb  = X + (size_t)b * N_TOK * C_;
  const ushort* wth = WT + (size_t)(h * D_) * C_;

  int arow = (wave << 5) + (lane & 31);
  int hi   = lane >> 5;

  for (int kc = 0; kc < C_ / BK; ++kc) {
    if (kc) __syncthreads();

    // --- stage A: gather 128 rows x 64 fp32, convert to bf16 ---
    float4 av[8];
#pragma unroll
    for (int rr = 0; rr < 8; ++rr) {
      int row = rr * 16 + r16;
      int idx = inds[row];
      av[rr] = *reinterpret_cast<const float4*>(
          &Xb[(size_t)idx * C_ + kc * BK + c4 * 4]);
    }
    // --- stage B: WT bf16 rows (contiguous) ---
    uint4 bvv[2];
#pragma unroll
    for (int t2 = 0; t2 < 2; ++t2) {
      int lin = tid + 256 * t2;
      int n  = lin >> 3;
      int cc = lin & 7;
      bvv[t2] = *reinterpret_cast<const uint4*>(&wth[n * C_ + kc * BK + cc * 8]);
    }
#pragma unroll
    for (int rr = 0; rr < 8; ++rr) {
      int row = rr * 16 + r16;
      ushort4 w;
      w.x = f2b(av[rr].x); w.y = f2b(av[rr].y);
      w.z = f2b(av[rr].z); w.w = f2b(av[rr].w);
      int sw = (c4 >> 1) ^ (row & 7);                 // 16B-chunk XOR swizzle
      *reinterpret_cast<ushort4*>(&Asu[row * 64 + sw * 8 + (c4 & 1) * 4]) = w;
    }
#pragma unroll
    for (int t2 = 0; t2 < 2; ++t2) {
      int lin = tid + 256 * t2;
      int n  = lin >> 3;
      int cc = lin & 7;
      *reinterpret_cast<uint4*>(&Bsu[n * 64 + ((cc ^ (n & 7)) << 3)]) = bvv[t2];
    }
    __syncthreads();

    // --- compute: 4 x (2 mfma 32x32x16) over this 64-wide K chunk ---
#pragma unroll
    for (int kk = 0; kk < 4; ++kk) {
      int ka = kk * 2 + hi;                            // 16B chunk index in row
      short8 af = *reinterpret_cast<short8*>(
          &Asu[arow * 64 + ((ka ^ (arow & 7)) << 3)]);
      int n0  = lane & 31;
      int swb = (ka ^ (n0 & 7)) << 3;
      short8 bf0 = *reinterpret_cast<short8*>(&Bsu[n0 * 64 + swb]);
      short8 bf1 = *reinterpret_cast<short8*>(&Bsu[(n0 + 32) * 64 + swb]);
      acc0 = __builtin_amdgcn_mfma_f32_32x32x16_bf16(af, bf0, acc0, 0, 0, 0);
      acc1 = __builtin_amdgcn_mfma_f32_32x32x16_bf16(af, bf1, acc1, 0, 0, 0);
    }
  }

  // --- epilogue: C/D layout col=lane&31, row=(reg&3)+8*(reg>>2)+4*(lane>>5) ---
  size_t obase = ((size_t)(b * H_ + h) * K_TOK + mt * BM + (wave << 5)) * D_;
  int col = lane & 31;
#pragma unroll
  for (int reg = 0; reg < 16; ++reg) {
    int r = (reg & 3) + 8 * (reg >> 2) + 4 * hi;
    out[obase + (size_t)r * D_ + col]      = acc0[reg];
    out[obase + (size_t)r * D_ + 32 + col] = acc1[reg];
  }
}

extern "C" void kernel_launch(void* const* d_in, const int* in_sizes, int n_in,
                              void* d_out, int out_size, void* d_ws, size_t ws_size,
                              hipStream_t stream) {
  const float* X  = (const float*)d_in[0];
  const int*  ind = (const int*)d_in[1];
  const float* W  = (const float*)d_in[2];
  float* out = (float*)d_out;
  ushort* WT = (ushort*)d_ws;  // 1 MB bf16 [H][D][C]

  wt_convert<<<dim3(2048), dim3(256), 0, stream>>>(W, WT);
  gather_gemm<<<dim3(1024), dim3(256), 0, stream>>>(X, ind, WT, out);
}